// Round 4
// baseline (251.727 us; speedup 1.0000x reference)
//
#include <hip/hip_runtime.h>
#include <hip/hip_bf16.h>

// ---------------------------------------------------------------------------
// AttentionLayer: out = quirky_softmax(mask * (Q K^T)) @ V
//   denom[j] = sum_k exp(mask[j,k]*S[j,k])  (row sums)
//   softmax[i,j] = E[i,j] / denom[j]        (column-indexed denom!)
//   => out = E @ (V scaled per-row by 1/denom)
// R4: E + scaled-V in fp8 e4m3; out-GEMM in fp8 MFMA (verified, kept).
// R5-R7: three pipeline approximations all null at ~550 TF (m233's 2-phase
//     ceiling). R8: faithful m201 8-phase choreography:
//     - 4 phases/K-tile; per phase stage ONE 16KB half + ds_read NEXT
//       phase's A-quad; MFMA operands always read one phase earlier.
//     - A/B halves stripe-interleaved (32-row stripes) so wave-quad q only
//       needs half (q&1) -> 1-phase-lead reads are half-consistent.
//     - vmcnt(2) at p0/p3 only (counted ledger, never drains in steady
//       state); 2 barriers/phase; lgkmcnt(0)+sched_barrier before MFMA.
// ---------------------------------------------------------------------------

#define N_TOK 4096
#define D_DIM 1024
#define VS_SCALE 131072.0f        // 2^17: lifts V/denom (~7e-6) into fp8 range

typedef __bf16 bf16x8 __attribute__((ext_vector_type(8)));
typedef __bf16 bf16x4 __attribute__((ext_vector_type(4)));
typedef float  f32x4  __attribute__((ext_vector_type(4)));

typedef const __attribute__((address_space(1))) char g_char;
typedef __attribute__((address_space(3))) char lds_char;

__device__ inline unsigned char f32_to_fp8(float f) {
    return (unsigned char)(__builtin_amdgcn_cvt_pk_fp8_f32(f, f, 0, false) & 0xff);
}

// ---------------------------------------------------------------------------
// fp32 -> bf16 convert (blocks 0..4095) + bias concat (blocks 4096..4107)
// ---------------------------------------------------------------------------
__global__ void cvt_and_bias(const float* __restrict__ x, __bf16* __restrict__ xb,
                             const float* __restrict__ bq, const float* __restrict__ bk,
                             const float* __restrict__ bv, float* __restrict__ bcat) {
    int b = blockIdx.x;
    if (b < 4096) {
        int i = (b * 256 + threadIdx.x) * 4;
        float4 v = *(const float4*)(x + i);
        bf16x4 o;
        o.x = (__bf16)v.x; o.y = (__bf16)v.y;
        o.z = (__bf16)v.z; o.w = (__bf16)v.w;
        *(bf16x4*)(xb + i) = o;
    } else {
        int i = (b - 4096) * 256 + threadIdx.x;
        if (i < 1024) bcat[i] = bq[i];
        else if (i < 2048) bcat[i] = bk[i - 1024];
        else if (i < 3072) bcat[i] = bv[i - 2048];
    }
}

// ---------------------------------------------------------------------------
// Transpose three 1024x1024 fp32 W -> bf16 [out][in], concatenated
// ---------------------------------------------------------------------------
__global__ void transpose_w3(const float* __restrict__ Wq, const float* __restrict__ Wk,
                             const float* __restrict__ Wv, __bf16* __restrict__ outT) {
    const float* in = (blockIdx.z == 0) ? Wq : (blockIdx.z == 1) ? Wk : Wv;
    __bf16* oT = outT + (size_t)blockIdx.z * 1024 * 1024;
    __shared__ float t[64][65];
    const int c0 = blockIdx.x * 64, r0 = blockIdx.y * 64;
    const int tid = threadIdx.x;
#pragma unroll
    for (int k = 0; k < 16; k++) {
        int lin = tid + k * 256;
        int r = lin >> 6, c = lin & 63;
        t[r][c] = in[(size_t)(r0 + r) * 1024 + c0 + c];
    }
    __syncthreads();
#pragma unroll
    for (int k = 0; k < 16; k++) {
        int lin = tid + k * 256;
        int c = lin >> 6, r = lin & 63;
        oT[(size_t)(c0 + c) * 1024 + r0 + r] = (__bf16)t[r][c];
    }
}

// ---------------------------------------------------------------------------
// VsT[d][j] = fp8( VS_SCALE * V[j][d] / denom[j] ), V row stride ldv
// ---------------------------------------------------------------------------
__global__ void scale_transpose(const __bf16* __restrict__ V, int ldv,
                                const float* __restrict__ denom,
                                unsigned char* __restrict__ VT8) {
    __shared__ float t[64][65];
    __shared__ float rd[64];
    const int d0 = blockIdx.x * 64, j0 = blockIdx.y * 64;
    const int tid = threadIdx.x;
    if (tid < 64) rd[tid] = VS_SCALE / denom[j0 + tid];
    __syncthreads();
#pragma unroll
    for (int k = 0; k < 16; k++) {
        int lin = tid + k * 256;
        int j = lin >> 6, d = lin & 63;
        t[j][d] = (float)V[(size_t)(j0 + j) * ldv + d0 + d] * rd[j];
    }
    __syncthreads();
#pragma unroll
    for (int k = 0; k < 16; k++) {
        int lin = tid + k * 256;
        int d = lin >> 6, j = lin & 63;
        VT8[(size_t)(d0 + d) * N_TOK + j0 + j] = f32_to_fp8(t[j][d]);
    }
}

// ---------------------------------------------------------------------------
// NT GEMM (bf16): C = A * B^T, fp32 acc. 256x256 tile, BK=64, 512 thr/8
// waves (2Mx4N), per-wave 128x64. LDS = 2 dbuf x 64KB (A 32K + B 32K).
// Halves are 32-row-stripe-interleaved: half h = stripes s with s&1==h.
//   => wave row-quad q lives entirely in A-half (q&1); wave's B col-frags
//      j in B-half ((j>>1)&1).
// Stage order per tile t (halves of t+1): p0:B-odd p1:A-even p2:B-even
// p3:A-odd (2 gload_lds each). vmcnt(2) at p0/p3 after own stage-issue:
//   p3 forces {B-odd,A-even,B-even}(t+1);  p0 forces A-odd(t).
// Reads one phase ahead: p(q) MFMAs quad q with frags read at p(q-1);
// p0 additionally reads all 8 B-frags of tile t (self-waited via lgkm0).
// Swizzle (rule #21): rows 128B = 8 chunks; global chunk c of LDS row rl
// at slot c^(rl&7); pre-swizzled global source, linear gload_lds dest;
// read XORs l16&7 (bank-conflict-free, measured 0 in R6/R7).
// EPI 0: Cb = bf16(acc + bias[col])
// EPI 1: C8 = fp8(exp(mask[idx]*acc)); denom[row] += rowsum (atomic)
// ---------------------------------------------------------------------------
template <int EPI>
__global__ __launch_bounds__(512, 1)
void gemm_nt_256(const __bf16* __restrict__ A, const __bf16* __restrict__ B,
                 int lda, int ldb, int ldc, int K,
                 const float* __restrict__ bias,
                 const float* __restrict__ mask,
                 __bf16* __restrict__ Cb, unsigned char* __restrict__ C8,
                 float* __restrict__ denom) {
    __shared__ __bf16 ldsb[2 * 32768];   // 2 dbuf x 64 KB = 128 KB

    const int tid  = threadIdx.x;
    const int wave = tid >> 6;
    const int lane = tid & 63;
    const int quad = lane >> 4;
    const int l16  = lane & 15;
    const int l7   = l16 & 7;

    // bijective XCD swizzle on linear block id (nwg % 8 == 0 at our grids)
    const int nbx = gridDim.x;
    const int nwg = gridDim.x * gridDim.y;
    const int bid = blockIdx.y * nbx + blockIdx.x;
    const int cpx = nwg >> 3;
    const int swz = (bid & 7) * cpx + (bid >> 3);
    const int m0 = (swz / nbx) * 256;
    const int n0 = (swz % nbx) * 256;

    const int wg = wave >> 2;           // A row group (0/1)
    const int wr = wg * 128;
    const int wc = (wave & 3) * 64;     // B col group

    // ---- staging addresses ----
    // per gload: 512thr x 16B = 8KB = 64 rows-in-half x 128B. thread:
    // trow = tid>>3 (row-in-gload), chunk = tid&7 (linear LDS dest);
    // global chunk = (tid&7) ^ (trow&7) (pre-swizzle).
    // row-in-half q -> global row: (q>>5)*64 + h*32 + (q&31); with
    // q = g2*64 + trow:  grow = base0 + h*32 + g2*128,
    // base0 = (trow&31) | ((trow&32)<<1).
    const size_t lda_b = (size_t)lda * 2;
    const size_t ldb_b = (size_t)ldb * 2;
    const int trow  = tid >> 3;
    const int base0 = (trow & 31) | ((trow & 32) << 1);
    const int cg    = ((tid & 7) ^ (trow & 7)) * 16;
    const char* gAt = (const char*)A + (size_t)(m0 + base0) * lda_b + cg;
    const char* gBt = (const char*)B + (size_t)(n0 + base0) * ldb_b + cg;
    const size_t a32 = (size_t)32 * lda_b,  a128 = (size_t)128 * lda_b;
    const size_t b32 = (size_t)32 * ldb_b,  b128 = (size_t)128 * ldb_b;

    lds_char* lwA = (lds_char*)(void*)ldsb + tid * 16;          // A region
    lds_char* lwB = lwA + 32768;                                 // B region

    // ---- read addressing ----
    // A frag i (rows wr+16i+l16): half=(i>>1)&1, rl = 64*wg +(i>>2)*32
    //   +(i&1)*16 + l16;  byte = half*16384 + rl*128 + chunk-swz
    // B frag j (rows wc+16j+l16): half=(j>>1)&1, rl = (wc>>6)*32
    //   +(j&1)*16 + l16;  byte = 32768 + half*16384 + rl*128 + chunk-swz
    const int cs0 = (quad ^ l7) * 16;         // kstep 0 chunks 0..3
    const int cs1 = ((4 + quad) ^ l7) * 16;   // kstep 1 chunks 4..7
    const int aRowB = (wg * 64 + l16) * 128;
    const int bRowB = 32768 + ((wc >> 6) * 32 + l16) * 128;

#define AOFF(i) (((i >> 1) & 1) * 16384 + aRowB + (((i >> 2) * 32 + ((i) & 1) * 16) * 128))
#define BOFF(j) ((((j) >> 1) & 1) * 16384 + bRowB + ((((j) & 1) * 16) * 128))

    f32x4 acc[8][4];
#pragma unroll
    for (int i = 0; i < 8; i++)
#pragma unroll
        for (int j = 0; j < 4; j++) acc[i][j] = (f32x4){0.f, 0.f, 0.f, 0.f};

    bf16x8 aA[2][2], aB[2][2], bfr[4][2];

    const int NT = K >> 6;
    const char* lbase = (const char*)(const void*)ldsb;

#define STG_A(h, tt, dd) do {                                                        \
    const char* ga_ = gAt + (size_t)(h) * a32 + (size_t)(tt) * 128;                  \
    lds_char* l_ = lwA + (dd) * 65536 + (h) * 16384;                                 \
    __builtin_amdgcn_global_load_lds((g_char*)ga_,          l_,        16, 0, 0);    \
    __builtin_amdgcn_global_load_lds((g_char*)(ga_ + a128), l_ + 8192, 16, 0, 0);    \
} while (0)
#define STG_B(h, tt, dd) do {                                                        \
    const char* gb_ = gBt + (size_t)(h) * b32 + (size_t)(tt) * 128;                  \
    lds_char* l_ = lwB + (dd) * 65536 + (h) * 16384;                                 \
    __builtin_amdgcn_global_load_lds((g_char*)gb_,          l_,        16, 0, 0);    \
    __builtin_amdgcn_global_load_lds((g_char*)(gb_ + b128), l_ + 8192, 16, 0, 0);    \
} while (0)

#define LDA2(dst, f0, f1, SB) do {                                                   \
    dst[0][0] = *(const bf16x8*)((SB) + AOFF(f0) + cs0);                             \
    dst[0][1] = *(const bf16x8*)((SB) + AOFF(f0) + cs1);                             \
    dst[1][0] = *(const bf16x8*)((SB) + AOFF(f1) + cs0);                             \
    dst[1][1] = *(const bf16x8*)((SB) + AOFF(f1) + cs1);                             \
} while (0)
#define LDB_ALL(SB) do {                                                             \
    _Pragma("unroll")                                                                \
    for (int j = 0; j < 4; j++) {                                                    \
        bfr[j][0] = *(const bf16x8*)((SB) + BOFF(j) + cs0);                          \
        bfr[j][1] = *(const bf16x8*)((SB) + BOFF(j) + cs1);                          \
    }                                                                                \
} while (0)
#define MF_QUAD(q, aX) do {                                                          \
    _Pragma("unroll")                                                                \
    for (int ii = 0; ii < 2; ii++)                                                   \
    _Pragma("unroll")                                                                \
    for (int j = 0; j < 4; j++) {                                                    \
        acc[2*(q)+ii][j] = __builtin_amdgcn_mfma_f32_16x16x32_bf16(                  \
            aX[ii][0], bfr[j][0], acc[2*(q)+ii][j], 0, 0, 0);                        \
        acc[2*(q)+ii][j] = __builtin_amdgcn_mfma_f32_16x16x32_bf16(                  \
            aX[ii][1], bfr[j][1], acc[2*(q)+ii][j], 0, 0, 0);                        \
    }                                                                                \
} while (0)
#define PHASE_SYNC_PRE()  do { __builtin_amdgcn_s_barrier();                         \
    asm volatile("s_waitcnt lgkmcnt(0)" ::: "memory");                               \
    __builtin_amdgcn_sched_barrier(0);                                               \
    __builtin_amdgcn_s_setprio(1); } while (0)
#define PHASE_SYNC_POST() do { __builtin_amdgcn_s_setprio(0);                        \
    __builtin_amdgcn_sched_barrier(0);                                               \
    __builtin_amdgcn_s_barrier(); } while (0)

    // ---- prologue: stage all 4 halves of tile 0, drain once, read aA(q0) ----
    STG_B(1, 0, 0);
    STG_A(0, 0, 0);
    STG_B(0, 0, 0);
    STG_A(1, 0, 0);
    asm volatile("s_waitcnt vmcnt(0)" ::: "memory");
    __builtin_amdgcn_s_barrier();
    LDA2(aA, 0, 1, lbase);

    for (int t = 0; t < NT; ++t) {
        const int d = t & 1;
        const char* sb  = lbase + d * 65536;
        const char* sbn = lbase + (d ^ 1) * 65536;
        const int dn = d ^ 1;
        const int tn = t + 1;
        const bool pf = (tn < NT);

        // ---- phase 0: MFMA quad0(aA); read B(t) + aB=frags{2,3}(t) ----
        if (pf) {
            STG_B(1, tn, dn);
            asm volatile("s_waitcnt vmcnt(2)" ::: "memory");
        } else {
            asm volatile("s_waitcnt vmcnt(0)" ::: "memory");
        }
        LDB_ALL(sb);
        LDA2(aB, 2, 3, sb);
        PHASE_SYNC_PRE();
        MF_QUAD(0, aA);
        PHASE_SYNC_POST();

        // ---- phase 1: MFMA quad1(aB); read aA=frags{4,5}(t) ----
        if (pf) STG_A(0, tn, dn);
        LDA2(aA, 4, 5, sb);
        PHASE_SYNC_PRE();
        MF_QUAD(1, aB);
        PHASE_SYNC_POST();

        // ---- phase 2: MFMA quad2(aA); read aB=frags{6,7}(t) ----
        if (pf) STG_B(0, tn, dn);
        LDA2(aB, 6, 7, sb);
        PHASE_SYNC_PRE();
        MF_QUAD(2, aA);
        PHASE_SYNC_POST();

        // ---- phase 3: MFMA quad3(aB); read aA=frags{0,1}(t+1) ----
        if (pf) {
            STG_A(1, tn, dn);
            asm volatile("s_waitcnt vmcnt(2)" ::: "memory");
            LDA2(aA, 0, 1, sbn);
        }
        PHASE_SYNC_PRE();
        MF_QUAD(3, aB);
        PHASE_SYNC_POST();
    }
#undef STG_A
#undef STG_B
#undef LDA2
#undef LDB_ALL
#undef MF_QUAD
#undef PHASE_SYNC_PRE
#undef PHASE_SYNC_POST
#undef AOFF
#undef BOFF

    // epilogue: C/D layout col=lane&15, row=quad*4+reg
#pragma unroll
    for (int i = 0; i < 8; i++) {
        const int rbase = m0 + wr + i * 16 + quad * 4;
        f32x4 rs = (f32x4){0.f, 0.f, 0.f, 0.f};
#pragma unroll
        for (int j = 0; j < 4; j++) {
            const int col = n0 + wc + j * 16 + l16;
            f32x4 v = acc[i][j];
            if (EPI == 0) {
                const float bb = bias[col];
#pragma unroll
                for (int r = 0; r < 4; r++)
                    Cb[(size_t)(rbase + r) * ldc + col] = (__bf16)(v[r] + bb);
            } else {
#pragma unroll
                for (int r = 0; r < 4; r++) {
                    size_t idx = (size_t)(rbase + r) * ldc + col;
                    float e = __expf(mask[idx] * v[r]);
                    C8[idx] = f32_to_fp8(e);
                    rs[r] += e;   // pre-round sum: bias contribution ~5e-6, negligible
                }
            }
        }
        if (EPI == 1) {
#pragma unroll
            for (int m = 1; m < 16; m <<= 1) {
#pragma unroll
                for (int r = 0; r < 4; r++) rs[r] += __shfl_xor(rs[r], m, 64);
            }
            if (l16 == 0) {
#pragma unroll
                for (int r = 0; r < 4; r++) atomicAdd(&denom[rbase + r], rs[r]);
            }
        }
    }
}

// ---------------------------------------------------------------------------
// out GEMM (fp8): C[4096][1024] = E[4096][4096] * VsT[1024][4096]^T, BK=128.
// 128x64 tile, 4 waves each 64x32 (4x2 frags). (R0-verified version.)
// ---------------------------------------------------------------------------
__global__ __launch_bounds__(256, 2)
void gemm_out_fp8(const unsigned char* __restrict__ A,
                  const unsigned char* __restrict__ B,
                  float* __restrict__ C) {
    __shared__ unsigned char lA[128 * 128];
    __shared__ unsigned char lB[64 * 128];

    const int tid  = threadIdx.x;
    const int wave = tid >> 6;
    const int lane = tid & 63;
    const int quad = lane >> 4;
    const int l16  = lane & 15;
    const int m0 = blockIdx.y * 128;
    const int n0 = blockIdx.x * 64;
    const int wr = (wave >> 1) * 64;
    const int wc = (wave & 1) * 32;

    const int tr = tid >> 3;
    const int ts = ((tid & 7) ^ (tr & 7)) * 16;
    const char* gA = (const char*)A + (size_t)(m0 + tr) * N_TOK + ts;
    const char* gB = (const char*)B + (size_t)(n0 + tr) * N_TOK + ts;
    const size_t pstep = (size_t)32 * N_TOK;

    lds_char* lAp = (lds_char*)(void*)lA + wave * 1024;
    lds_char* lBp = (lds_char*)(void*)lB + wave * 1024;

    // read addr: row*128 + ((kstep*2 + (quad>>1)) ^ (l16&7))*16 + (quad&1)*8
    const int l7 = l16 & 7;
    const int qhi = quad >> 1, qlo = (quad & 1) * 8;
    int rdA[4], rdB[4];
#pragma unroll
    for (int k = 0; k < 4; k++) {
        rdA[k] = ((k * 2 + qhi) ^ l7) * 16 + qlo;   // add row*128 per-frag
        rdB[k] = rdA[k];
    }

    f32x4 acc[4][2];
#pragma unroll
    for (int i = 0; i < 4; i++)
#pragma unroll
        for (int j = 0; j < 2; j++) acc[i][j] = (f32x4){0.f, 0.f, 0.f, 0.f};

    for (int kt = 0; kt < N_TOK; kt += 128) {
#pragma unroll
        for (int c = 0; c < 4; c++)
            __builtin_amdgcn_global_load_lds((g_char*)(gA + c * pstep),
                                             lAp + c * 4096, 16, 0, 0);
#pragma unroll
        for (int c = 0; c < 2; c++)
            __builtin_amdgcn_global_load_lds((g_char*)(gB + c * pstep),
                                             lBp + c * 4096, 16, 0, 0);
        gA += 128;
        gB += 128;
        __syncthreads();

#pragma unroll
        for (int k = 0; k < 4; k++) {
            long a[4], b[2];
#pragma unroll
            for (int i = 0; i < 4; i++)
                a[i] = *(const long*)&lA[(wr + i * 16 + l16) * 128 + rdA[k]];
#pragma unroll
            for (int j = 0; j < 2; j++)
                b[j] = *(const long*)&lB[(wc + j * 16 + l16) * 128 + rdB[k]];
#pragma unroll
            for (int i = 0; i < 4; i++)
#pragma unroll
                for (int j = 0; j < 2; j++)
                    acc[i][j] = __builtin_amdgcn_mfma_f32_16x16x32_fp8_fp8(
                        a[i], b[j], acc[i][j], 0, 0, 0);
        }
        __syncthreads();
    }

#pragma unroll
    for (int i = 0; i < 4; i++) {
#pragma unroll
        for (int j = 0; j < 2; j++) {
            const int col   = n0 + wc + j * 16 + l16;
            const int rbase = m0 + wr + i * 16 + quad * 4;
            f32x4 v = acc[i][j];
#pragma unroll
            for (int r = 0; r < 4; r++)
                C[(size_t)(rbase + r) * D_DIM + col] = v[r] * (1.0f / VS_SCALE);
        }
    }
}

// ---------------------------------------------------------------------------
extern "C" void kernel_launch(void* const* d_in, const int* in_sizes, int n_in,
                              void* d_out, int out_size, void* d_ws, size_t ws_size,
                              hipStream_t stream) {
    const float* x    = (const float*)d_in[0];
    const float* mask = (const float*)d_in[1];
    const float* Wq   = (const float*)d_in[2];
    const float* bq   = (const float*)d_in[3];
    const float* Wk   = (const float*)d_in[4];
    const float* bk   = (const float*)d_in[5];
    const float* Wv   = (const float*)d_in[6];
    const float* bv   = (const float*)d_in[7];
    float* out = (float*)d_out;
    char* ws = (char*)d_ws;

    const size_t MB = 1024 * 1024;
    unsigned char* E8   = (unsigned char*)(ws + 0 * MB);   // 16 MB [4096][4096] fp8
    __bf16* QKVb  = (__bf16*)(ws + 16 * MB);               // 24 MB [4096][3072]
    __bf16* xb    = (__bf16*)(ws + 40 * MB);               // 8 MB [4096][1024]
    unsigned char* VsT8 = (unsigned char*)xb;              // 4 MB (reuses dead xb)
    __bf16* WcatT = (__bf16*)(ws + 48 * MB);               // 6 MB [3072][1024]
    float*  bcat  = (float*)(ws + 54 * MB);                // 12 KB
    float*  denom = (float*)(ws + 54 * MB + 64 * 1024);    // 16 KB

    hipMemsetAsync(denom, 0, N_TOK * sizeof(float), stream);

    // ---- prep ----
    cvt_and_bias<<<4096 + 12, 256, 0, stream>>>(x, xb, bq, bk, bv, bcat);
    transpose_w3<<<dim3(16, 16, 3), 256, 0, stream>>>(Wq, Wk, Wv, WcatT);

    // ---- fused QKV projection: [4096][3072] = xb @ WcatT^T ----
    gemm_nt_256<0><<<dim3(12, 16), 512, 0, stream>>>(
        xb, WcatT, D_DIM, D_DIM, 3 * D_DIM, D_DIM,
        bcat, nullptr, QKVb, nullptr, nullptr);

    // ---- E = exp(mask * (Q K^T)) -> fp8; denom[row] += rowsum ----
    const __bf16* Qb = QKVb;
    const __bf16* Kb = QKVb + D_DIM;
    gemm_nt_256<1><<<dim3(16, 16), 512, 0, stream>>>(
        Qb, Kb, 3 * D_DIM, 3 * D_DIM, N_TOK, D_DIM,
        nullptr, mask, nullptr, E8, denom);

    // ---- VsT8[d][j] = fp8(VS_SCALE * V[j][d] / denom[j]) ----
    scale_transpose<<<dim3(16, 64), 256, 0, stream>>>(QKVb + 2048, 3 * D_DIM, denom, VsT8);

    // ---- out = (E8 @ VsT8^T) / VS_SCALE ----
    gemm_out_fp8<<<dim3(16, 32), 256, 0, stream>>>(E8, VsT8, out);
}

// Round 5
// 249.188 us; speedup vs baseline: 1.0102x; 1.0102x over previous
//
#include <hip/hip_runtime.h>
#include <hip/hip_bf16.h>

// ---------------------------------------------------------------------------
// AttentionLayer: out = quirky_softmax(mask * (Q K^T)) @ V
//   denom[j] = sum_k exp(mask[j,k]*S[j,k])  (row sums)
//   softmax[i,j] = E[i,j] / denom[j]        (column-indexed denom!)
//   => out = E @ (V scaled per-row by 1/denom)
// R4: E + scaled-V in fp8 e4m3; out-GEMM in fp8 MFMA (verified, kept).
// R5-R8: four K-loop schedule variants all null at ~62us -> K-loop is NOT
//     the dominant term. FETCH (~70MB) is mostly the 64MB fp32 mask read,
//     done serially in the epilogue.
// R9: (a) EPI1 epilogue pipelined: 2-deep register prefetch of mask chunks
//     (16 scalars/chunk, static unroll) so the 64MB read overlaps exp/store;
//     (b) kernels name-split (gemm_qkv / gemm_qkt) for per-dispatch rocprof.
//     K-loop = R8 verified code, untouched.
// ---------------------------------------------------------------------------

#define N_TOK 4096
#define D_DIM 1024
#define VS_SCALE 131072.0f        // 2^17: lifts V/denom (~7e-6) into fp8 range

typedef __bf16 bf16x8 __attribute__((ext_vector_type(8)));
typedef __bf16 bf16x4 __attribute__((ext_vector_type(4)));
typedef float  f32x4  __attribute__((ext_vector_type(4)));

typedef const __attribute__((address_space(1))) char g_char;
typedef __attribute__((address_space(3))) char lds_char;

__device__ inline unsigned char f32_to_fp8(float f) {
    return (unsigned char)(__builtin_amdgcn_cvt_pk_fp8_f32(f, f, 0, false) & 0xff);
}

// ---------------------------------------------------------------------------
// fp32 -> bf16 convert (blocks 0..4095) + bias concat (blocks 4096..4107)
// ---------------------------------------------------------------------------
__global__ void cvt_and_bias(const float* __restrict__ x, __bf16* __restrict__ xb,
                             const float* __restrict__ bq, const float* __restrict__ bk,
                             const float* __restrict__ bv, float* __restrict__ bcat) {
    int b = blockIdx.x;
    if (b < 4096) {
        int i = (b * 256 + threadIdx.x) * 4;
        float4 v = *(const float4*)(x + i);
        bf16x4 o;
        o.x = (__bf16)v.x; o.y = (__bf16)v.y;
        o.z = (__bf16)v.z; o.w = (__bf16)v.w;
        *(bf16x4*)(xb + i) = o;
    } else {
        int i = (b - 4096) * 256 + threadIdx.x;
        if (i < 1024) bcat[i] = bq[i];
        else if (i < 2048) bcat[i] = bk[i - 1024];
        else if (i < 3072) bcat[i] = bv[i - 2048];
    }
}

// ---------------------------------------------------------------------------
// Transpose three 1024x1024 fp32 W -> bf16 [out][in], concatenated
// ---------------------------------------------------------------------------
__global__ void transpose_w3(const float* __restrict__ Wq, const float* __restrict__ Wk,
                             const float* __restrict__ Wv, __bf16* __restrict__ outT) {
    const float* in = (blockIdx.z == 0) ? Wq : (blockIdx.z == 1) ? Wk : Wv;
    __bf16* oT = outT + (size_t)blockIdx.z * 1024 * 1024;
    __shared__ float t[64][65];
    const int c0 = blockIdx.x * 64, r0 = blockIdx.y * 64;
    const int tid = threadIdx.x;
#pragma unroll
    for (int k = 0; k < 16; k++) {
        int lin = tid + k * 256;
        int r = lin >> 6, c = lin & 63;
        t[r][c] = in[(size_t)(r0 + r) * 1024 + c0 + c];
    }
    __syncthreads();
#pragma unroll
    for (int k = 0; k < 16; k++) {
        int lin = tid + k * 256;
        int c = lin >> 6, r = lin & 63;
        oT[(size_t)(c0 + c) * 1024 + r0 + r] = (__bf16)t[r][c];
    }
}

// ---------------------------------------------------------------------------
// VsT[d][j] = fp8( VS_SCALE * V[j][d] / denom[j] ), V row stride ldv
// ---------------------------------------------------------------------------
__global__ void scale_transpose(const __bf16* __restrict__ V, int ldv,
                                const float* __restrict__ denom,
                                unsigned char* __restrict__ VT8) {
    __shared__ float t[64][65];
    __shared__ float rd[64];
    const int d0 = blockIdx.x * 64, j0 = blockIdx.y * 64;
    const int tid = threadIdx.x;
    if (tid < 64) rd[tid] = VS_SCALE / denom[j0 + tid];
    __syncthreads();
#pragma unroll
    for (int k = 0; k < 16; k++) {
        int lin = tid + k * 256;
        int j = lin >> 6, d = lin & 63;
        t[j][d] = (float)V[(size_t)(j0 + j) * ldv + d0 + d] * rd[j];
    }
    __syncthreads();
#pragma unroll
    for (int k = 0; k < 16; k++) {
        int lin = tid + k * 256;
        int d = lin >> 6, j = lin & 63;
        VT8[(size_t)(d0 + d) * N_TOK + j0 + j] = f32_to_fp8(t[j][d]);
    }
}

// ---------------------------------------------------------------------------
// NT GEMM body (bf16): C = A * B^T, fp32 acc. 256x256 tile, BK=64, 512 thr/8
// waves (2Mx4N), per-wave 128x64. LDS = 2 dbuf x 64KB. R8-verified 8-phase
// choreography (stripe-interleaved halves, 1-phase-lead reads, counted
// vmcnt(2) at p0/p3). See R8 notes. K-loop unchanged from R8.
// EPI 0: Cb = bf16(acc + bias[col])
// EPI 1: C8 = fp8(exp(mask*acc)); denom[row] += rowsum. Epilogue is a 2-deep
//        register-prefetch pipeline over 8 chunks of 16 mask scalars.
// ---------------------------------------------------------------------------
template <int EPI>
__device__ __forceinline__
void gemm_nt_body(const __bf16* __restrict__ A, const __bf16* __restrict__ B,
                  int lda, int ldb, int ldc, int K,
                  const float* __restrict__ bias,
                  const float* __restrict__ mask,
                  __bf16* __restrict__ Cb, unsigned char* __restrict__ C8,
                  float* __restrict__ denom) {
    __shared__ __bf16 ldsb[2 * 32768];   // 2 dbuf x 64 KB = 128 KB

    const int tid  = threadIdx.x;
    const int wave = tid >> 6;
    const int lane = tid & 63;
    const int quad = lane >> 4;
    const int l16  = lane & 15;
    const int l7   = l16 & 7;

    // bijective XCD swizzle on linear block id (nwg % 8 == 0 at our grids)
    const int nbx = gridDim.x;
    const int nwg = gridDim.x * gridDim.y;
    const int bid = blockIdx.y * nbx + blockIdx.x;
    const int cpx = nwg >> 3;
    const int swz = (bid & 7) * cpx + (bid >> 3);
    const int m0 = (swz / nbx) * 256;
    const int n0 = (swz % nbx) * 256;

    const int wg = wave >> 2;           // A row group (0/1)
    const int wr = wg * 128;
    const int wc = (wave & 3) * 64;     // B col group

    const size_t lda_b = (size_t)lda * 2;
    const size_t ldb_b = (size_t)ldb * 2;
    const int trow  = tid >> 3;
    const int base0 = (trow & 31) | ((trow & 32) << 1);
    const int cg    = ((tid & 7) ^ (trow & 7)) * 16;
    const char* gAt = (const char*)A + (size_t)(m0 + base0) * lda_b + cg;
    const char* gBt = (const char*)B + (size_t)(n0 + base0) * ldb_b + cg;
    const size_t a32 = (size_t)32 * lda_b,  a128 = (size_t)128 * lda_b;
    const size_t b32 = (size_t)32 * ldb_b,  b128 = (size_t)128 * ldb_b;

    lds_char* lwA = (lds_char*)(void*)ldsb + tid * 16;          // A region
    lds_char* lwB = lwA + 32768;                                 // B region

    const int cs0 = (quad ^ l7) * 16;         // kstep 0 chunks 0..3
    const int cs1 = ((4 + quad) ^ l7) * 16;   // kstep 1 chunks 4..7
    const int aRowB = (wg * 64 + l16) * 128;
    const int bRowB = 32768 + ((wc >> 6) * 32 + l16) * 128;

#define AOFF(i) (((i >> 1) & 1) * 16384 + aRowB + (((i >> 2) * 32 + ((i) & 1) * 16) * 128))
#define BOFF(j) ((((j) >> 1) & 1) * 16384 + bRowB + ((((j) & 1) * 16) * 128))

    f32x4 acc[8][4];
#pragma unroll
    for (int i = 0; i < 8; i++)
#pragma unroll
        for (int j = 0; j < 4; j++) acc[i][j] = (f32x4){0.f, 0.f, 0.f, 0.f};

    bf16x8 aA[2][2], aB[2][2], bfr[4][2];

    const int NT = K >> 6;
    const char* lbase = (const char*)(const void*)ldsb;

#define STG_A(h, tt, dd) do {                                                        \
    const char* ga_ = gAt + (size_t)(h) * a32 + (size_t)(tt) * 128;                  \
    lds_char* l_ = lwA + (dd) * 65536 + (h) * 16384;                                 \
    __builtin_amdgcn_global_load_lds((g_char*)ga_,          l_,        16, 0, 0);    \
    __builtin_amdgcn_global_load_lds((g_char*)(ga_ + a128), l_ + 8192, 16, 0, 0);    \
} while (0)
#define STG_B(h, tt, dd) do {                                                        \
    const char* gb_ = gBt + (size_t)(h) * b32 + (size_t)(tt) * 128;                  \
    lds_char* l_ = lwB + (dd) * 65536 + (h) * 16384;                                 \
    __builtin_amdgcn_global_load_lds((g_char*)gb_,          l_,        16, 0, 0);    \
    __builtin_amdgcn_global_load_lds((g_char*)(gb_ + b128), l_ + 8192, 16, 0, 0);    \
} while (0)

#define LDA2(dst, f0, f1, SB) do {                                                   \
    dst[0][0] = *(const bf16x8*)((SB) + AOFF(f0) + cs0);                             \
    dst[0][1] = *(const bf16x8*)((SB) + AOFF(f0) + cs1);                             \
    dst[1][0] = *(const bf16x8*)((SB) + AOFF(f1) + cs0);                             \
    dst[1][1] = *(const bf16x8*)((SB) + AOFF(f1) + cs1);                             \
} while (0)
#define LDB_ALL(SB) do {                                                             \
    _Pragma("unroll")                                                                \
    for (int j = 0; j < 4; j++) {                                                    \
        bfr[j][0] = *(const bf16x8*)((SB) + BOFF(j) + cs0);                          \
        bfr[j][1] = *(const bf16x8*)((SB) + BOFF(j) + cs1);                          \
    }                                                                                \
} while (0)
#define MF_QUAD(q, aX) do {                                                          \
    _Pragma("unroll")                                                                \
    for (int ii = 0; ii < 2; ii++)                                                   \
    _Pragma("unroll")                                                                \
    for (int j = 0; j < 4; j++) {                                                    \
        acc[2*(q)+ii][j] = __builtin_amdgcn_mfma_f32_16x16x32_bf16(                  \
            aX[ii][0], bfr[j][0], acc[2*(q)+ii][j], 0, 0, 0);                        \
        acc[2*(q)+ii][j] = __builtin_amdgcn_mfma_f32_16x16x32_bf16(                  \
            aX[ii][1], bfr[j][1], acc[2*(q)+ii][j], 0, 0, 0);                        \
    }                                                                                \
} while (0)
#define PHASE_SYNC_PRE()  do { __builtin_amdgcn_s_barrier();                         \
    asm volatile("s_waitcnt lgkmcnt(0)" ::: "memory");                               \
    __builtin_amdgcn_sched_barrier(0);                                               \
    __builtin_amdgcn_s_setprio(1); } while (0)
#define PHASE_SYNC_POST() do { __builtin_amdgcn_s_setprio(0);                        \
    __builtin_amdgcn_sched_barrier(0);                                               \
    __builtin_amdgcn_s_barrier(); } while (0)

    // ---- prologue: stage all 4 halves of tile 0, drain once, read aA(q0) ----
    STG_B(1, 0, 0);
    STG_A(0, 0, 0);
    STG_B(0, 0, 0);
    STG_A(1, 0, 0);
    asm volatile("s_waitcnt vmcnt(0)" ::: "memory");
    __builtin_amdgcn_s_barrier();
    LDA2(aA, 0, 1, lbase);

    for (int t = 0; t < NT; ++t) {
        const int d = t & 1;
        const char* sb  = lbase + d * 65536;
        const char* sbn = lbase + (d ^ 1) * 65536;
        const int dn = d ^ 1;
        const int tn = t + 1;
        const bool pf = (tn < NT);

        // ---- phase 0: MFMA quad0(aA); read B(t) + aB=frags{2,3}(t) ----
        if (pf) {
            STG_B(1, tn, dn);
            asm volatile("s_waitcnt vmcnt(2)" ::: "memory");
        } else {
            asm volatile("s_waitcnt vmcnt(0)" ::: "memory");
        }
        LDB_ALL(sb);
        LDA2(aB, 2, 3, sb);
        PHASE_SYNC_PRE();
        MF_QUAD(0, aA);
        PHASE_SYNC_POST();

        // ---- phase 1: MFMA quad1(aB); read aA=frags{4,5}(t) ----
        if (pf) STG_A(0, tn, dn);
        LDA2(aA, 4, 5, sb);
        PHASE_SYNC_PRE();
        MF_QUAD(1, aB);
        PHASE_SYNC_POST();

        // ---- phase 2: MFMA quad2(aA); read aB=frags{6,7}(t) ----
        if (pf) STG_B(0, tn, dn);
        LDA2(aB, 6, 7, sb);
        PHASE_SYNC_PRE();
        MF_QUAD(2, aA);
        PHASE_SYNC_POST();

        // ---- phase 3: MFMA quad3(aB); read aA=frags{0,1}(t+1) ----
        if (pf) {
            STG_A(1, tn, dn);
            asm volatile("s_waitcnt vmcnt(2)" ::: "memory");
            LDA2(aA, 0, 1, sbn);
        }
        PHASE_SYNC_PRE();
        MF_QUAD(3, aB);
        PHASE_SYNC_POST();
    }
#undef STG_A
#undef STG_B
#undef LDA2
#undef LDB_ALL
#undef MF_QUAD
#undef PHASE_SYNC_PRE
#undef PHASE_SYNC_POST
#undef AOFF
#undef BOFF

    // ---- epilogue: C/D layout col=lane&15, row=quad*4+reg ----
    if (EPI == 0) {
#pragma unroll
        for (int i = 0; i < 8; i++) {
            const int rbase = m0 + wr + i * 16 + quad * 4;
#pragma unroll
            for (int j = 0; j < 4; j++) {
                const int col = n0 + wc + j * 16 + l16;
                f32x4 v = acc[i][j];
                const float bb = bias[col];
#pragma unroll
                for (int r = 0; r < 4; r++)
                    Cb[(size_t)(rbase + r) * ldc + col] = (__bf16)(v[r] + bb);
            }
        }
    } else {
        // 2-deep chunk-pipelined mask prefetch: chunk i = 16 scalars
        // (j=0..3, r=0..3) for output row-group i. Loads for chunk i+1 are
        // issued BEFORE consuming chunk i; sched_barrier(0) per step stops
        // mass-hoisting (VGPR blowup). All indices compile-time (rule #20).
        const float* mrow = mask + (size_t)(m0 + wr + quad * 4) * (size_t)ldc
                            + (n0 + wc + l16);
        unsigned char* crow = C8 + (size_t)(m0 + wr + quad * 4) * (size_t)ldc
                            + (n0 + wc + l16);
        float mk0[4][4], mk1[4][4];
#define LOADC(dst, ii) do {                                                         \
    _Pragma("unroll")                                                               \
    for (int j = 0; j < 4; j++)                                                     \
    _Pragma("unroll")                                                               \
    for (int r = 0; r < 4; r++)                                                     \
        dst[j][r] = mrow[(size_t)((ii) * 16 + r) * (size_t)ldc + j * 16];           \
} while (0)
#define CONSUME(ii, mk) do {                                                        \
    f32x4 rs = (f32x4){0.f, 0.f, 0.f, 0.f};                                         \
    _Pragma("unroll")                                                               \
    for (int j = 0; j < 4; j++) {                                                   \
        f32x4 v = acc[ii][j];                                                       \
        _Pragma("unroll")                                                           \
        for (int r = 0; r < 4; r++) {                                               \
            float e = __expf(mk[j][r] * v[r]);                                      \
            crow[(size_t)((ii) * 16 + r) * (size_t)ldc + j * 16] = f32_to_fp8(e);   \
            rs[r] += e;                                                             \
        }                                                                           \
    }                                                                               \
    _Pragma("unroll")                                                               \
    for (int m = 1; m < 16; m <<= 1)                                                \
        _Pragma("unroll")                                                           \
        for (int r = 0; r < 4; r++) rs[r] += __shfl_xor(rs[r], m, 64);              \
    if (l16 == 0) {                                                                 \
        const int rb = m0 + wr + (ii) * 16 + quad * 4;                              \
        _Pragma("unroll")                                                           \
        for (int r = 0; r < 4; r++) atomicAdd(&denom[rb + r], rs[r]);               \
    }                                                                               \
} while (0)
        LOADC(mk0, 0);
        LOADC(mk1, 1);
        CONSUME(0, mk0); __builtin_amdgcn_sched_barrier(0);
        LOADC(mk0, 2);
        CONSUME(1, mk1); __builtin_amdgcn_sched_barrier(0);
        LOADC(mk1, 3);
        CONSUME(2, mk0); __builtin_amdgcn_sched_barrier(0);
        LOADC(mk0, 4);
        CONSUME(3, mk1); __builtin_amdgcn_sched_barrier(0);
        LOADC(mk1, 5);
        CONSUME(4, mk0); __builtin_amdgcn_sched_barrier(0);
        LOADC(mk0, 6);
        CONSUME(5, mk1); __builtin_amdgcn_sched_barrier(0);
        LOADC(mk1, 7);
        CONSUME(6, mk0); __builtin_amdgcn_sched_barrier(0);
        CONSUME(7, mk1);
#undef LOADC
#undef CONSUME
    }
}

// ---- named wrappers (distinct rocprof rows) ----
__global__ __launch_bounds__(512, 1)
void gemm_qkv(const __bf16* __restrict__ A, const __bf16* __restrict__ B,
              int lda, int ldb, int ldc, int K,
              const float* __restrict__ bias,
              __bf16* __restrict__ Cb) {
    gemm_nt_body<0>(A, B, lda, ldb, ldc, K, bias, nullptr, Cb, nullptr, nullptr);
}

__global__ __launch_bounds__(512, 1)
void gemm_qkt(const __bf16* __restrict__ A, const __bf16* __restrict__ B,
              int lda, int ldb, int ldc, int K,
              const float* __restrict__ mask,
              unsigned char* __restrict__ C8, float* __restrict__ denom) {
    gemm_nt_body<1>(A, B, lda, ldb, ldc, K, nullptr, mask, nullptr, C8, denom);
}

// ---------------------------------------------------------------------------
// out GEMM (fp8): C[4096][1024] = E[4096][4096] * VsT[1024][4096]^T, BK=128.
// 128x64 tile, 4 waves each 64x32 (4x2 frags). (R0-verified version.)
// ---------------------------------------------------------------------------
__global__ __launch_bounds__(256, 2)
void gemm_out_fp8(const unsigned char* __restrict__ A,
                  const unsigned char* __restrict__ B,
                  float* __restrict__ C) {
    __shared__ unsigned char lA[128 * 128];
    __shared__ unsigned char lB[64 * 128];

    const int tid  = threadIdx.x;
    const int wave = tid >> 6;
    const int lane = tid & 63;
    const int quad = lane >> 4;
    const int l16  = lane & 15;
    const int m0 = blockIdx.y * 128;
    const int n0 = blockIdx.x * 64;
    const int wr = (wave >> 1) * 64;
    const int wc = (wave & 1) * 32;

    const int tr = tid >> 3;
    const int ts = ((tid & 7) ^ (tr & 7)) * 16;
    const char* gA = (const char*)A + (size_t)(m0 + tr) * N_TOK + ts;
    const char* gB = (const char*)B + (size_t)(n0 + tr) * N_TOK + ts;
    const size_t pstep = (size_t)32 * N_TOK;

    lds_char* lAp = (lds_char*)(void*)lA + wave * 1024;
    lds_char* lBp = (lds_char*)(void*)lB + wave * 1024;

    // read addr: row*128 + ((kstep*2 + (quad>>1)) ^ (l16&7))*16 + (quad&1)*8
    const int l7 = l16 & 7;
    const int qhi = quad >> 1, qlo = (quad & 1) * 8;
    int rdA[4], rdB[4];
#pragma unroll
    for (int k = 0; k < 4; k++) {
        rdA[k] = ((k * 2 + qhi) ^ l7) * 16 + qlo;   // add row*128 per-frag
        rdB[k] = rdA[k];
    }

    f32x4 acc[4][2];
#pragma unroll
    for (int i = 0; i < 4; i++)
#pragma unroll
        for (int j = 0; j < 2; j++) acc[i][j] = (f32x4){0.f, 0.f, 0.f, 0.f};

    for (int kt = 0; kt < N_TOK; kt += 128) {
#pragma unroll
        for (int c = 0; c < 4; c++)
            __builtin_amdgcn_global_load_lds((g_char*)(gA + c * pstep),
                                             lAp + c * 4096, 16, 0, 0);
#pragma unroll
        for (int c = 0; c < 2; c++)
            __builtin_amdgcn_global_load_lds((g_char*)(gB + c * pstep),
                                             lBp + c * 4096, 16, 0, 0);
        gA += 128;
        gB += 128;
        __syncthreads();

#pragma unroll
        for (int k = 0; k < 4; k++) {
            long a[4], b[2];
#pragma unroll
            for (int i = 0; i < 4; i++)
                a[i] = *(const long*)&lA[(wr + i * 16 + l16) * 128 + rdA[k]];
#pragma unroll
            for (int j = 0; j < 2; j++)
                b[j] = *(const long*)&lB[(wc + j * 16 + l16) * 128 + rdB[k]];
#pragma unroll
            for (int i = 0; i < 4; i++)
#pragma unroll
                for (int j = 0; j < 2; j++)
                    acc[i][j] = __builtin_amdgcn_mfma_f32_16x16x32_fp8_fp8(
                        a[i], b[j], acc[i][j], 0, 0, 0);
        }
        __syncthreads();
    }

#pragma unroll
    for (int i = 0; i < 4; i++) {
#pragma unroll
        for (int j = 0; j < 2; j++) {
            const int col   = n0 + wc + j * 16 + l16;
            const int rbase = m0 + wr + i * 16 + quad * 4;
            f32x4 v = acc[i][j];
#pragma unroll
            for (int r = 0; r < 4; r++)
                C[(size_t)(rbase + r) * D_DIM + col] = v[r] * (1.0f / VS_SCALE);
        }
    }
}

// ---------------------------------------------------------------------------
extern "C" void kernel_launch(void* const* d_in, const int* in_sizes, int n_in,
                              void* d_out, int out_size, void* d_ws, size_t ws_size,
                              hipStream_t stream) {
    const float* x    = (const float*)d_in[0];
    const float* mask = (const float*)d_in[1];
    const float* Wq   = (const float*)d_in[2];
    const float* bq   = (const float*)d_in[3];
    const float* Wk   = (const float*)d_in[4];
    const float* bk   = (const float*)d_in[5];
    const float* Wv   = (const float*)d_in[6];
    const float* bv   = (const float*)d_in[7];
    float* out = (float*)d_out;
    char* ws = (char*)d_ws;

    const size_t MB = 1024 * 1024;
    unsigned char* E8   = (unsigned char*)(ws + 0 * MB);   // 16 MB [4096][4096] fp8
    __bf16* QKVb  = (__bf16*)(ws + 16 * MB);               // 24 MB [4096][3072]
    __bf16* xb    = (__bf16*)(ws + 40 * MB);               // 8 MB [4096][1024]
    unsigned char* VsT8 = (unsigned char*)xb;              // 4 MB (reuses dead xb)
    __bf16* WcatT = (__bf16*)(ws + 48 * MB);               // 6 MB [3072][1024]
    float*  bcat  = (float*)(ws + 54 * MB);                // 12 KB
    float*  denom = (float*)(ws + 54 * MB + 64 * 1024);    // 16 KB

    hipMemsetAsync(denom, 0, N_TOK * sizeof(float), stream);

    // ---- prep ----
    cvt_and_bias<<<4096 + 12, 256, 0, stream>>>(x, xb, bq, bk, bv, bcat);
    transpose_w3<<<dim3(16, 16, 3), 256, 0, stream>>>(Wq, Wk, Wv, WcatT);

    // ---- fused QKV projection: [4096][3072] = xb @ WcatT^T ----
    gemm_qkv<<<dim3(12, 16), 512, 0, stream>>>(
        xb, WcatT, D_DIM, D_DIM, 3 * D_DIM, D_DIM, bcat, QKVb);

    // ---- E = exp(mask * (Q K^T)) -> fp8; denom[row] += rowsum ----
    const __bf16* Qb = QKVb;
    const __bf16* Kb = QKVb + D_DIM;
    gemm_qkt<<<dim3(16, 16), 512, 0, stream>>>(
        Qb, Kb, 3 * D_DIM, 3 * D_DIM, N_TOK, D_DIM, mask, E8, denom);

    // ---- VsT8[d][j] = fp8(VS_SCALE * V[j][d] / denom[j]) ----
    scale_transpose<<<dim3(16, 64), 256, 0, stream>>>(QKVb + 2048, 3 * D_DIM, denom, VsT8);

    // ---- out = (E8 @ VsT8^T) / VS_SCALE ----
    gemm_out_fp8<<<dim3(16, 32), 256, 0, stream>>>(E8, VsT8, out);
}

// Round 6
// 248.801 us; speedup vs baseline: 1.0118x; 1.0016x over previous
//
#include <hip/hip_runtime.h>
#include <hip/hip_bf16.h>

// ---------------------------------------------------------------------------
// AttentionLayer: out = quirky_softmax(mask * (Q K^T)) @ V
//   denom[j] = sum_k exp(mask[j,k]*S[j,k])  (row sums)
//   softmax[i,j] = E[i,j] / denom[j]        (column-indexed denom!)
//   => out = E @ (V scaled per-row by 1/denom)
// R4: E + scaled-V in fp8 e4m3; out-GEMM in fp8 MFMA (verified, kept).
// R5-R9: all K-loop variants drained lgkmcnt(0) on same-phase reads ->
//     every phase exposed the full ds_read latency; MfmaUtil pinned ~21%
//     (12.9us MFMA-busy == near-perfect pipe 21% of the time).
// R10: counted waits on BOTH counters. BK=32 4-slot ring (R7 addressing,
//     0 bank conflicts) with: vmcnt(4) -> barrier (publish) -> stage h+3 ->
//     read B(h)[4] + A(h+1)[8, floats] -> lgkmcnt(8) (forces A(h)+B(h)) ->
//     32 MFMA on prev-phase A regs. A ping-pong, one barrier/phase,
//     no drain until tail.
// ---------------------------------------------------------------------------

#define N_TOK 4096
#define D_DIM 1024
#define VS_SCALE 131072.0f        // 2^17: lifts V/denom (~7e-6) into fp8 range

typedef __bf16 bf16x8 __attribute__((ext_vector_type(8)));
typedef __bf16 bf16x4 __attribute__((ext_vector_type(4)));
typedef float  f32x4  __attribute__((ext_vector_type(4)));

typedef const __attribute__((address_space(1))) char g_char;
typedef __attribute__((address_space(3))) char lds_char;

__device__ inline unsigned char f32_to_fp8(float f) {
    return (unsigned char)(__builtin_amdgcn_cvt_pk_fp8_f32(f, f, 0, false) & 0xff);
}

// ---------------------------------------------------------------------------
// fp32 -> bf16 convert (blocks 0..4095) + bias concat (blocks 4096..4107)
// ---------------------------------------------------------------------------
__global__ void cvt_and_bias(const float* __restrict__ x, __bf16* __restrict__ xb,
                             const float* __restrict__ bq, const float* __restrict__ bk,
                             const float* __restrict__ bv, float* __restrict__ bcat) {
    int b = blockIdx.x;
    if (b < 4096) {
        int i = (b * 256 + threadIdx.x) * 4;
        float4 v = *(const float4*)(x + i);
        bf16x4 o;
        o.x = (__bf16)v.x; o.y = (__bf16)v.y;
        o.z = (__bf16)v.z; o.w = (__bf16)v.w;
        *(bf16x4*)(xb + i) = o;
    } else {
        int i = (b - 4096) * 256 + threadIdx.x;
        if (i < 1024) bcat[i] = bq[i];
        else if (i < 2048) bcat[i] = bk[i - 1024];
        else if (i < 3072) bcat[i] = bv[i - 2048];
    }
}

// ---------------------------------------------------------------------------
// Transpose three 1024x1024 fp32 W -> bf16 [out][in], concatenated
// ---------------------------------------------------------------------------
__global__ void transpose_w3(const float* __restrict__ Wq, const float* __restrict__ Wk,
                             const float* __restrict__ Wv, __bf16* __restrict__ outT) {
    const float* in = (blockIdx.z == 0) ? Wq : (blockIdx.z == 1) ? Wk : Wv;
    __bf16* oT = outT + (size_t)blockIdx.z * 1024 * 1024;
    __shared__ float t[64][65];
    const int c0 = blockIdx.x * 64, r0 = blockIdx.y * 64;
    const int tid = threadIdx.x;
#pragma unroll
    for (int k = 0; k < 16; k++) {
        int lin = tid + k * 256;
        int r = lin >> 6, c = lin & 63;
        t[r][c] = in[(size_t)(r0 + r) * 1024 + c0 + c];
    }
    __syncthreads();
#pragma unroll
    for (int k = 0; k < 16; k++) {
        int lin = tid + k * 256;
        int c = lin >> 6, r = lin & 63;
        oT[(size_t)(c0 + c) * 1024 + r0 + r] = (__bf16)t[r][c];
    }
}

// ---------------------------------------------------------------------------
// VsT[d][j] = fp8( VS_SCALE * V[j][d] / denom[j] ), V row stride ldv
// ---------------------------------------------------------------------------
__global__ void scale_transpose(const __bf16* __restrict__ V, int ldv,
                                const float* __restrict__ denom,
                                unsigned char* __restrict__ VT8) {
    __shared__ float t[64][65];
    __shared__ float rd[64];
    const int d0 = blockIdx.x * 64, j0 = blockIdx.y * 64;
    const int tid = threadIdx.x;
    if (tid < 64) rd[tid] = VS_SCALE / denom[j0 + tid];
    __syncthreads();
#pragma unroll
    for (int k = 0; k < 16; k++) {
        int lin = tid + k * 256;
        int j = lin >> 6, d = lin & 63;
        t[j][d] = (float)V[(size_t)(j0 + j) * ldv + d0 + d] * rd[j];
    }
    __syncthreads();
#pragma unroll
    for (int k = 0; k < 16; k++) {
        int lin = tid + k * 256;
        int d = lin >> 6, j = lin & 63;
        VT8[(size_t)(d0 + d) * N_TOK + j0 + j] = f32_to_fp8(t[j][d]);
    }
}

// ---------------------------------------------------------------------------
// NT GEMM body (bf16): C = A * B^T, fp32 acc. 256x256 tile, 512 thr / 8
// waves (2Mx4N), per-wave 128x64. Counted-vmcnt + counted-lgkm ring:
//   staging unit = BK=32 half-tile: A 256x32 (16KB) + B 64..256x32 -> one
//   32KB slot; ring of 4 slots = 128 KB LDS.
//   phase h: [vmcnt(4): forces slot h+1 (this wave); slot h+2 floats]
//            -> s_barrier (publishes slot h+1 cross-wave)
//            -> stage slot h+3 (4 gloads)
//            -> ds_read B(h) [4] + A(h+1) [8, into other A-set]
//            -> lgkmcnt(8): forces A(h) (read last phase) + B(h);
//               the 8 A(h+1) reads float a full phase
//            -> setprio(1), 32 MFMA on A(h)+B(h), setprio(0)
//   Tail peels vmcnt(4)->vmcnt(0) and lgkm(8)->lgkm(0).
// Swizzle (rule #21): rows are 64B = 4x16B chunks; global chunk c of row r
// stored at LDS chunk c ^ ((r>>1)&3); read XORs the same -> 2-way (free);
// measured 0 conflicts in R7.
// EPI 0: Cb = bf16(acc + bias[col])
// EPI 1: C8 = fp8(exp(mask*acc)); denom[row] += rowsum (atomic)
// ---------------------------------------------------------------------------
template <int EPI>
__device__ __forceinline__
void gemm_nt_body(const __bf16* __restrict__ A, const __bf16* __restrict__ B,
                  int lda, int ldb, int ldc, int K,
                  const float* __restrict__ bias,
                  const float* __restrict__ mask,
                  __bf16* __restrict__ Cb, unsigned char* __restrict__ C8,
                  float* __restrict__ denom) {
    __shared__ __bf16 ldsb[4 * 16384];   // 4 slots x 32 KB = 128 KB

    const int tid  = threadIdx.x;
    const int wave = tid >> 6;
    const int lane = tid & 63;
    const int quad = lane >> 4;
    const int l16  = lane & 15;

    // bijective XCD swizzle on linear block id (nwg % 8 == 0 at our grids)
    const int nbx = gridDim.x;
    const int nwg = gridDim.x * gridDim.y;
    const int bid = blockIdx.y * nbx + blockIdx.x;
    const int cpx = nwg >> 3;
    const int swz = (bid & 7) * cpx + (bid >> 3);
    const int m0 = (swz / nbx) * 256;
    const int n0 = (swz % nbx) * 256;

    const int wr = (wave >> 2) * 128;   // 2 row groups
    const int wc = (wave & 3) * 64;     // 4 col groups

    // ---- staging addresses (R7-verified) ----
    // round = 512 thr x 16B = 8 KB = 128 rows x 64 B. thread t: row t>>2,
    // LDS chunk t&3 (linear dest), global chunk (t&3)^((t>>3)&3).
    const size_t lda_b = (size_t)lda * 2;
    const size_t ldb_b = (size_t)ldb * 2;
    const int trow = tid >> 2;
    const int tcs  = ((tid & 3) ^ ((tid >> 3) & 3)) * 16;
    const char* gA = (const char*)A + (size_t)(m0 + trow) * lda_b + tcs;
    const char* gB = (const char*)B + (size_t)(n0 + trow) * ldb_b + tcs;
    const size_t rstepA = 128 * lda_b;
    const size_t rstepB = 128 * ldb_b;

    lds_char* lw = (lds_char*)(void*)ldsb + tid * 16;

    // ---- read addresses (R7-verified, 0 bank conflicts) ----
    const int cswz = (quad ^ ((l16 >> 1) & 3)) * 16;
    const int aOff = (wr + l16) * 64 + cswz;            // + i*1024 per frag
    const int bOff = (wc + l16) * 64 + cswz + 16384;    // + j*1024 per frag

    f32x4 acc[8][4];
#pragma unroll
    for (int i = 0; i < 8; i++)
#pragma unroll
        for (int j = 0; j < 4; j++) acc[i][j] = (f32x4){0.f, 0.f, 0.f, 0.f};

    const int H = K >> 5;   // number of BK=32 slots (=32 at K=1024)
    const char* lbase = (const char*)(const void*)ldsb;

    bf16x8 a0[8], a1[8], bC[4];

#define STAGEH(hh) do {                                                              \
    const char* ga_ = gA + (size_t)(hh) * 64;                                        \
    const char* gb_ = gB + (size_t)(hh) * 64;                                        \
    lds_char* ls_ = lw + ((hh) & 3) * 32768;                                         \
    __builtin_amdgcn_global_load_lds((g_char*)(ga_),          ls_,          16, 0, 0); \
    __builtin_amdgcn_global_load_lds((g_char*)(ga_ + rstepA), ls_ + 8192,   16, 0, 0); \
    __builtin_amdgcn_global_load_lds((g_char*)(gb_),          ls_ + 16384,  16, 0, 0); \
    __builtin_amdgcn_global_load_lds((g_char*)(gb_ + rstepB), ls_ + 24576,  16, 0, 0); \
} while (0)

#define READ_A8(AV, slot) do {                                                       \
    const char* sb_ = lbase + (slot) * 32768;                                        \
    _Pragma("unroll")                                                                \
    for (int i_ = 0; i_ < 8; i_++)                                                   \
        AV[i_] = *(const bf16x8*)(sb_ + aOff + i_ * 1024);                           \
} while (0)

#define READ_B4(slot) do {                                                           \
    const char* sb_ = lbase + (slot) * 32768;                                        \
    _Pragma("unroll")                                                                \
    for (int j_ = 0; j_ < 4; j_++)                                                   \
        bC[j_] = *(const bf16x8*)(sb_ + bOff + j_ * 1024);                           \
} while (0)

#define MFMA32(AU) do {                                                              \
    _Pragma("unroll")                                                                \
    for (int i_ = 0; i_ < 8; i_++)                                                   \
    _Pragma("unroll")                                                                \
    for (int j_ = 0; j_ < 4; j_++)                                                   \
        acc[i_][j_] = __builtin_amdgcn_mfma_f32_16x16x32_bf16(                       \
            AU[i_], bC[j_], acc[i_][j_], 0, 0, 0);                                   \
} while (0)

    // phase h: MFMA uses A-set read last phase; reads next slot's A into AV.
#define PHASE(hh, AU, AV) do {                                                       \
    const bool pf1_ = (hh) + 1 < H;                                                  \
    const bool pf2_ = (hh) + 2 < H;                                                  \
    if (pf1_) {                                                                      \
        if (pf2_) asm volatile("s_waitcnt vmcnt(4)" ::: "memory");                   \
        else      asm volatile("s_waitcnt vmcnt(0)" ::: "memory");                   \
    }                                                                                \
    __builtin_amdgcn_s_barrier();                                                    \
    if ((hh) + 3 < H) STAGEH((hh) + 3);                                              \
    READ_B4((hh) & 3);                                                               \
    if (pf1_) READ_A8(AV, ((hh) + 1) & 3);                                           \
    if (pf1_) asm volatile("s_waitcnt lgkmcnt(8)" ::: "memory");                     \
    else      asm volatile("s_waitcnt lgkmcnt(0)" ::: "memory");                     \
    __builtin_amdgcn_sched_barrier(0);                                               \
    __builtin_amdgcn_s_setprio(1);                                                   \
    MFMA32(AU);                                                                      \
    __builtin_amdgcn_s_setprio(0);                                                   \
    __builtin_amdgcn_sched_barrier(0);                                               \
} while (0)

    // prologue: stage slots 0,1,2 (12 loads); force slot0; publish; read A(0)
    STAGEH(0);
    STAGEH(1);
    STAGEH(2);
    asm volatile("s_waitcnt vmcnt(8)" ::: "memory");
    __builtin_amdgcn_s_barrier();
    READ_A8(a0, 0);

    for (int h0 = 0; h0 < H; h0 += 2) {
        PHASE(h0,     a0, a1);
        PHASE(h0 + 1, a1, a0);
    }
#undef STAGEH
#undef READ_A8
#undef READ_B4
#undef MFMA32
#undef PHASE

    // ---- epilogue: C/D layout col=lane&15, row=quad*4+reg ----
    if (EPI == 0) {
#pragma unroll
        for (int i = 0; i < 8; i++) {
            const int rbase = m0 + wr + i * 16 + quad * 4;
#pragma unroll
            for (int j = 0; j < 4; j++) {
                const int col = n0 + wc + j * 16 + l16;
                f32x4 v = acc[i][j];
                const float bb = bias[col];
#pragma unroll
                for (int r = 0; r < 4; r++)
                    Cb[(size_t)(rbase + r) * ldc + col] = (__bf16)(v[r] + bb);
            }
        }
    } else {
        // 2-deep chunk-pipelined mask prefetch (R9).
        const float* mrow = mask + (size_t)(m0 + wr + quad * 4) * (size_t)ldc
                            + (n0 + wc + l16);
        unsigned char* crow = C8 + (size_t)(m0 + wr + quad * 4) * (size_t)ldc
                            + (n0 + wc + l16);
        float mk0[4][4], mk1[4][4];
#define LOADC(dst, ii) do {                                                         \
    _Pragma("unroll")                                                               \
    for (int j = 0; j < 4; j++)                                                     \
    _Pragma("unroll")                                                               \
    for (int r = 0; r < 4; r++)                                                     \
        dst[j][r] = mrow[(size_t)((ii) * 16 + r) * (size_t)ldc + j * 16];           \
} while (0)
#define CONSUME(ii, mk) do {                                                        \
    f32x4 rs = (f32x4){0.f, 0.f, 0.f, 0.f};                                         \
    _Pragma("unroll")                                                               \
    for (int j = 0; j < 4; j++) {                                                   \
        f32x4 v = acc[ii][j];                                                       \
        _Pragma("unroll")                                                           \
        for (int r = 0; r < 4; r++) {                                               \
            float e = __expf(mk[j][r] * v[r]);                                      \
            crow[(size_t)((ii) * 16 + r) * (size_t)ldc + j * 16] = f32_to_fp8(e);   \
            rs[r] += e;                                                             \
        }                                                                           \
    }                                                                               \
    _Pragma("unroll")                                                               \
    for (int m = 1; m < 16; m <<= 1)                                                \
        _Pragma("unroll")                                                           \
        for (int r = 0; r < 4; r++) rs[r] += __shfl_xor(rs[r], m, 64);              \
    if (l16 == 0) {                                                                 \
        const int rb = m0 + wr + (ii) * 16 + quad * 4;                              \
        _Pragma("unroll")                                                           \
        for (int r = 0; r < 4; r++) atomicAdd(&denom[rb + r], rs[r]);               \
    }                                                                               \
} while (0)
        LOADC(mk0, 0);
        LOADC(mk1, 1);
        CONSUME(0, mk0); __builtin_amdgcn_sched_barrier(0);
        LOADC(mk0, 2);
        CONSUME(1, mk1); __builtin_amdgcn_sched_barrier(0);
        LOADC(mk1, 3);
        CONSUME(2, mk0); __builtin_amdgcn_sched_barrier(0);
        LOADC(mk0, 4);
        CONSUME(3, mk1); __builtin_amdgcn_sched_barrier(0);
        LOADC(mk1, 5);
        CONSUME(4, mk0); __builtin_amdgcn_sched_barrier(0);
        LOADC(mk0, 6);
        CONSUME(5, mk1); __builtin_amdgcn_sched_barrier(0);
        LOADC(mk1, 7);
        CONSUME(6, mk0); __builtin_amdgcn_sched_barrier(0);
        CONSUME(7, mk1);
#undef LOADC
#undef CONSUME
    }
}

// ---- named wrappers (distinct rocprof rows) ----
__global__ __launch_bounds__(512, 1)
void gemm_qkv(const __bf16* __restrict__ A, const __bf16* __restrict__ B,
              int lda, int ldb, int ldc, int K,
              const float* __restrict__ bias,
              __bf16* __restrict__ Cb) {
    gemm_nt_body<0>(A, B, lda, ldb, ldc, K, bias, nullptr, Cb, nullptr, nullptr);
}

__global__ __launch_bounds__(512, 1)
void gemm_qkt(const __bf16* __restrict__ A, const __bf16* __restrict__ B,
              int lda, int ldb, int ldc, int K,
              const float* __restrict__ mask,
              unsigned char* __restrict__ C8, float* __restrict__ denom) {
    gemm_nt_body<1>(A, B, lda, ldb, ldc, K, nullptr, mask, nullptr, C8, denom);
}

// ---------------------------------------------------------------------------
// out GEMM (fp8): C[4096][1024] = E[4096][4096] * VsT[1024][4096]^T, BK=128.
// 128x64 tile, 4 waves each 64x32 (4x2 frags). (R0-verified version.)
// ---------------------------------------------------------------------------
__global__ __launch_bounds__(256, 2)
void gemm_out_fp8(const unsigned char* __restrict__ A,
                  const unsigned char* __restrict__ B,
                  float* __restrict__ C) {
    __shared__ unsigned char lA[128 * 128];
    __shared__ unsigned char lB[64 * 128];

    const int tid  = threadIdx.x;
    const int wave = tid >> 6;
    const int lane = tid & 63;
    const int quad = lane >> 4;
    const int l16  = lane & 15;
    const int m0 = blockIdx.y * 128;
    const int n0 = blockIdx.x * 64;
    const int wr = (wave >> 1) * 64;
    const int wc = (wave & 1) * 32;

    const int tr = tid >> 3;
    const int ts = ((tid & 7) ^ (tr & 7)) * 16;
    const char* gA = (const char*)A + (size_t)(m0 + tr) * N_TOK + ts;
    const char* gB = (const char*)B + (size_t)(n0 + tr) * N_TOK + ts;
    const size_t pstep = (size_t)32 * N_TOK;

    lds_char* lAp = (lds_char*)(void*)lA + wave * 1024;
    lds_char* lBp = (lds_char*)(void*)lB + wave * 1024;

    // read addr: row*128 + ((kstep*2 + (quad>>1)) ^ (l16&7))*16 + (quad&1)*8
    const int l7 = l16 & 7;
    const int qhi = quad >> 1, qlo = (quad & 1) * 8;
    int rdA[4], rdB[4];
#pragma unroll
    for (int k = 0; k < 4; k++) {
        rdA[k] = ((k * 2 + qhi) ^ l7) * 16 + qlo;   // add row*128 per-frag
        rdB[k] = rdA[k];
    }

    f32x4 acc[4][2];
#pragma unroll
    for (int i = 0; i < 4; i++)
#pragma unroll
        for (int j = 0; j < 2; j++) acc[i][j] = (f32x4){0.f, 0.f, 0.f, 0.f};

    for (int kt = 0; kt < N_TOK; kt += 128) {
#pragma unroll
        for (int c = 0; c < 4; c++)
            __builtin_amdgcn_global_load_lds((g_char*)(gA + c * pstep),
                                             lAp + c * 4096, 16, 0, 0);
#pragma unroll
        for (int c = 0; c < 2; c++)
            __builtin_amdgcn_global_load_lds((g_char*)(gB + c * pstep),
                                             lBp + c * 4096, 16, 0, 0);
        gA += 128;
        gB += 128;
        __syncthreads();

#pragma unroll
        for (int k = 0; k < 4; k++) {
            long a[4], b[2];
#pragma unroll
            for (int i = 0; i < 4; i++)
                a[i] = *(const long*)&lA[(wr + i * 16 + l16) * 128 + rdA[k]];
#pragma unroll
            for (int j = 0; j < 2; j++)
                b[j] = *(const long*)&lB[(wc + j * 16 + l16) * 128 + rdB[k]];
#pragma unroll
            for (int i = 0; i < 4; i++)
#pragma unroll
                for (int j = 0; j < 2; j++)
                    acc[i][j] = __builtin_amdgcn_mfma_f32_16x16x32_fp8_fp8(
                        a[i], b[j], acc[i][j], 0, 0, 0);
        }
        __syncthreads();
    }

#pragma unroll
    for (int i = 0; i < 4; i++) {
#pragma unroll
        for (int j = 0; j < 2; j++) {
            const int col   = n0 + wc + j * 16 + l16;
            const int rbase = m0 + wr + i * 16 + quad * 4;
            f32x4 v = acc[i][j];
#pragma unroll
            for (int r = 0; r < 4; r++)
                C[(size_t)(rbase + r) * D_DIM + col] = v[r] * (1.0f / VS_SCALE);
        }
    }
}

// ---------------------------------------------------------------------------
extern "C" void kernel_launch(void* const* d_in, const int* in_sizes, int n_in,
                              void* d_out, int out_size, void* d_ws, size_t ws_size,
                              hipStream_t stream) {
    const float* x    = (const float*)d_in[0];
    const float* mask = (const float*)d_in[1];
    const float* Wq   = (const float*)d_in[2];
    const float* bq   = (const float*)d_in[3];
    const float* Wk   = (const float*)d_in[4];
    const float* bk   = (const float*)d_in[5];
    const float* Wv   = (const float*)d_in[6];
    const float* bv   = (const float*)d_in[7];
    float* out = (float*)d_out;
    char* ws = (char*)d_ws;

    const size_t MB = 1024 * 1024;
    unsigned char* E8   = (unsigned char*)(ws + 0 * MB);   // 16 MB [4096][4096] fp8
    __bf16* QKVb  = (__bf16*)(ws + 16 * MB);               // 24 MB [4096][3072]
    __bf16* xb    = (__bf16*)(ws + 40 * MB);               // 8 MB [4096][1024]
    unsigned char* VsT8 = (unsigned char*)xb;              // 4 MB (reuses dead xb)
    __bf16* WcatT = (__bf16*)(ws + 48 * MB);               // 6 MB [3072][1024]
    float*  bcat  = (float*)(ws + 54 * MB);                // 12 KB
    float*  denom = (float*)(ws + 54 * MB + 64 * 1024);    // 16 KB

    hipMemsetAsync(denom, 0, N_TOK * sizeof(float), stream);

    // ---- prep ----
    cvt_and_bias<<<4096 + 12, 256, 0, stream>>>(x, xb, bq, bk, bv, bcat);
    transpose_w3<<<dim3(16, 16, 3), 256, 0, stream>>>(Wq, Wk, Wv, WcatT);

    // ---- fused QKV projection: [4096][3072] = xb @ WcatT^T ----
    gemm_qkv<<<dim3(12, 16), 512, 0, stream>>>(
        xb, WcatT, D_DIM, D_DIM, 3 * D_DIM, D_DIM, bcat, QKVb);

    // ---- E = exp(mask * (Q K^T)) -> fp8; denom[row] += rowsum ----
    const __bf16* Qb = QKVb;
    const __bf16* Kb = QKVb + D_DIM;
    gemm_qkt<<<dim3(16, 16), 512, 0, stream>>>(
        Qb, Kb, 3 * D_DIM, 3 * D_DIM, N_TOK, D_DIM, mask, E8, denom);

    // ---- VsT8[d][j] = fp8(VS_SCALE * V[j][d] / denom[j]) ----
    scale_transpose<<<dim3(16, 64), 256, 0, stream>>>(QKVb + 2048, 3 * D_DIM, denom, VsT8);

    // ---- out = (E8 @ VsT8^T) / VS_SCALE ----
    gemm_out_fp8<<<dim3(16, 32), 256, 0, stream>>>(E8, VsT8, out);
}